// Round 3
// baseline (97.639 us; speedup 1.0000x reference)
//
#include <hip/hip_runtime.h>

// InvButterflyLayer: B=256, MID=16384, OUT=16384, C=16, NLVL=8.
// Live cone: level lvl only needs t < 2^(8-lvl); level 0 t<256 -> x[0:8224).
//
// Kernel A: block=(b,i) [512 blocks x 256 thr]. Levels 0..3.
// Kernel B: block=(n4, bi-chunk of 32) [256 blocks x 512 thr]. Levels 4..8
//   + 16->64 dense + complex recombine, fused.
// Weights: wave-uniform node -> scalar (s_load) weights; non-uniform levels
// (3 and 8) staged in LDS (reads are wave-uniform-per-iteration -> broadcast).
//
// LDS state layout: vector v (16 floats) stored as 4 float4 chunks. Pair
// region {2h,2h+1} = 32 aligned floats; chunk q of v lives at slot
// (((v&1)<<2)|q) ^ ((h^(h>>3))&7). Bijective (XOR on addr bits[2:4] keyed by
// higher bits), float4-aligned, conflict-free for stride-1 and stride-2 reads.

#define OUT_HALF 2097152

__device__ __forceinline__ int paddr(int v, int q) {
    const int h    = v >> 1;
    const int slot = ((v & 1) << 2) | q;
    const int swz  = (h ^ (h >> 3)) & 7;
    return (h << 5) + ((slot ^ swz) << 2);
}

__device__ __forceinline__ void fma16(float* acc, float p, const float* w) {
#pragma unroll
    for (int d = 0; d < 16; d++) acc[d] += p * w[d];
}

__device__ __forceinline__ void store_relu(float* base, int v, const float* acc) {
#pragma unroll
    for (int q = 0; q < 4; q++) {
        *(float4*)(base + paddr(v, q)) =
            make_float4(fmaxf(acc[4 * q + 0], 0.f), fmaxf(acc[4 * q + 1], 0.f),
                        fmaxf(acc[4 * q + 2], 0.f), fmaxf(acc[4 * q + 3], 0.f));
    }
}

__global__ __launch_bounds__(256, 2)
void ibf_A(const float* __restrict__ in_data,
           const float* __restrict__ mid_dense,
           const float* __restrict__ in_filter,
           const float* __restrict__ in_bias,
           const float* __restrict__ filters,
           const float* __restrict__ biases,
           float* __restrict__ S3) {
    __shared__ __align__(16) float bufA[4096];
    __shared__ __align__(16) float bufB[4096];
    __shared__ __align__(16) float W3[4096];
    __shared__ float B3[128];

    const int tid = threadIdx.x;
    const int b   = blockIdx.x;
    const int i   = blockIdx.y;

    // stage lvl3 weights (8 nodes x 512) + biases; consumed after >=2 barriers
    {
        const float4* src = (const float4*)(filters + 2 * 131072);
        for (int x4 = tid; x4 < 1024; x4 += 256) ((float4*)W3)[x4] = src[x4];
        if (tid < 128) B3[tid] = biases[2 * 4096 + tid];
    }

    // ---- level 0: t = tid, 64-tap window at stride 32 ----
    {
        float acc[16];
#pragma unroll
        for (int c = 0; c < 16; c++) acc[c] = in_bias[c];
        const float4* inb = (const float4*)(in_data + ((size_t)b * 16384 + (size_t)32 * tid) * 2);
        const float4* mdb = (const float4*)(mid_dense + (size_t)(32 * tid) * 2);
#pragma unroll 8
        for (int w2 = 0; w2 < 32; w2++) {
            float4 iv = inb[w2];
            float4 mv = mdb[w2];
            float x0 = (i == 0) ? iv.x * mv.x : iv.y * mv.y;
            float x1 = (i == 0) ? iv.z * mv.z : iv.w * mv.w;
            const float* F0 = in_filter + (w2 * 2) * 16;   // uniform -> s_load
            fma16(acc, x0, F0);
            fma16(acc, x1, F0 + 16);
        }
        store_relu(bufA, tid, acc);
    }
    __syncthreads();

    // ---- levels 1,2: wave-uniform node -> scalar-load weights ----
    float* P = bufA;
    float* N = bufB;
#pragma unroll
    for (int lvl = 1; lvl <= 2; lvl++) {
        const int sh = 8 - lvl;
        const int T  = 1 << sh;
        const int n  = tid >> sh;
        const int t  = tid & (T - 1);
        const int nu = __builtin_amdgcn_readfirstlane((lvl - 1) * 256 + n);
        const float* Wn = filters + (size_t)nu * 512;
        const float* bn = biases + (size_t)nu * 16;
        float acc[16];
#pragma unroll
        for (int d = 0; d < 16; d++) acc[d] = bn[d];
        const int pb = (n >> 1) * (2 * T);
#pragma unroll
        for (int k = 0; k < 2; k++) {
            const int pv = pb + 2 * t + k;
#pragma unroll
            for (int cq = 0; cq < 4; cq++) {
                float4 pc = *(const float4*)(P + paddr(pv, cq));
                const float* w0 = Wn + k * 256 + cq * 64;
                fma16(acc, pc.x, w0);
                fma16(acc, pc.y, w0 + 16);
                fma16(acc, pc.z, w0 + 32);
                fma16(acc, pc.w, w0 + 48);
            }
        }
        store_relu(N, tid, acc);
        __syncthreads();
        float* tmp = P; P = N; N = tmp;
    }

    // ---- level 3: 2 nodes/wave -> LDS weights; store straight to global ----
    {
        const int n = tid >> 5;
        const int t = tid & 31;
        const float* Wn = W3 + n * 512;
        float acc[16];
#pragma unroll
        for (int d = 0; d < 16; d++) acc[d] = B3[n * 16 + d];
        const int pb = (n >> 1) * 64;
#pragma unroll
        for (int k = 0; k < 2; k++) {
            const int pv = pb + 2 * t + k;
#pragma unroll
            for (int cq = 0; cq < 4; cq++) {
                float4 pc = *(const float4*)(P + paddr(pv, cq));
                const float* w0 = Wn + k * 256 + cq * 64;
                fma16(acc, pc.x, w0);
                fma16(acc, pc.y, w0 + 16);
                fma16(acc, pc.z, w0 + 32);
                fma16(acc, pc.w, w0 + 48);
            }
        }
        float* dst = S3 + ((size_t)(2 * b + i) * 256 + tid) * 16;
#pragma unroll
        for (int d = 0; d < 16; d += 4) {
            ((float4*)dst)[d >> 2] = make_float4(fmaxf(acc[d], 0.f), fmaxf(acc[d + 1], 0.f),
                                                 fmaxf(acc[d + 2], 0.f), fmaxf(acc[d + 3], 0.f));
        }
    }
}

__global__ __launch_bounds__(512, 2)
void ibf_B(const float* __restrict__ filters,
           const float* __restrict__ biases,
           const float* __restrict__ fea_dense,
           const float* __restrict__ S3,
           float* __restrict__ out) {
    __shared__ __align__(16) float R1[16448];   // lvl3-in(1024v)/lvl5/lvl7, then FE
    __shared__ __align__(16) float R2[8192];    // lvl4 / lvl6 / feat(512v)
    __shared__ __align__(16) float W8[8192];
    __shared__ float B8[256];

    const int tid   = threadIdx.x;
    const int n4    = blockIdx.x;   // 0..15
    const int chunk = blockIdx.y;   // 0..15
    const int bi0   = chunk * 32;
    const int n3    = n4 >> 1;

    // ---- stage lvl3 input (32 t x 32 bi x 16), W8 (16 nodes), B8 ----
    {
        for (int idx = tid; idx < 4096; idx += 512) {
            const int bi_l = idx >> 7;
            const int r    = idx & 127;
            const int t3   = r >> 2;
            const int q    = r & 3;
            float4 v = *(const float4*)(S3 + ((size_t)(bi0 + bi_l) * 256 + n3 * 32 + t3) * 16 + 4 * q);
            *(float4*)(R1 + paddr(t3 * 32 + bi_l, q)) = v;
        }
        const float4* w8g = (const float4*)(filters + (size_t)7 * 131072 + (size_t)(n4 * 16) * 512);
        for (int idx = tid; idx < 2048; idx += 512) ((float4*)W8)[idx] = w8g[idx];
        if (tid < 256) B8[tid] = biases[7 * 4096 + n4 * 256 + tid];
    }
    __syncthreads();

    // ---- levels 4..7: wave-uniform node -> s_load weights ----
    float* P = R1;
    float* N = R2;
#pragma unroll
    for (int lvl = 4; lvl <= 7; lvl++) {
        const int Tsh   = 8 - lvl;               // T = 16,8,4,2
        const int n_loc = tid >> (Tsh + 5);
        const int t     = (tid >> 5) & ((1 << Tsh) - 1);
        const int bi    = tid & 31;
        const int ng    = (n4 << (lvl - 4)) + n_loc;
        const int nu    = __builtin_amdgcn_readfirstlane((lvl - 1) * 256 + ng);
        const float* Wn = filters + (size_t)nu * 512;
        const float* bn = biases + (size_t)nu * 16;
        float acc[16];
#pragma unroll
        for (int d = 0; d < 16; d++) acc[d] = bn[d];
        const int pb = (n_loc >> 1) << (Tsh + 6);  // (n_loc>>1) * (2T*32)
#pragma unroll
        for (int k = 0; k < 2; k++) {
            const int pv = pb + (2 * t + k) * 32 + bi;
#pragma unroll
            for (int cq = 0; cq < 4; cq++) {
                float4 pc = *(const float4*)(P + paddr(pv, cq));
                const float* w0 = Wn + k * 256 + cq * 64;
                fma16(acc, pc.x, w0);
                fma16(acc, pc.y, w0 + 16);
                fma16(acc, pc.z, w0 + 32);
                fma16(acc, pc.w, w0 + 48);
            }
        }
        store_relu(N, tid, acc);
        __syncthreads();
        float* tmp = P; P = N; N = tmp;
    }

    // ---- level 8 (t=0): 2 nodes/wave -> LDS weights; feat -> R2 ----
    {
        const int n8l = tid >> 5;
        const int bi  = tid & 31;
        const float* Wn = W8 + n8l * 512;
        float acc[16];
#pragma unroll
        for (int d = 0; d < 16; d++) acc[d] = B8[n8l * 16 + d];
        const int pb = (n8l >> 1) * 64;
#pragma unroll
        for (int k = 0; k < 2; k++) {
            const int pv = pb + k * 32 + bi;
#pragma unroll
            for (int cq = 0; cq < 4; cq++) {
                float4 pc = *(const float4*)(R1 + paddr(pv, cq));   // P == R1 here
                const float* w0 = Wn + k * 256 + cq * 64;
                fma16(acc, pc.x, w0);
                fma16(acc, pc.y, w0 + 16);
                fma16(acc, pc.z, w0 + 32);
                fma16(acc, pc.w, w0 + 48);
            }
        }
        store_relu(R2, tid, acc);
    }
    __syncthreads();

    // ---- stage fea_dense (16 nodes x 16c x 64u) into R1, node-stride 1028 ----
    {
        const float4* feg = (const float4*)(fea_dense + (size_t)(n4 * 16) * 1024);
        for (int idx = tid; idx < 4096; idx += 512) {
            const int fi = idx * 4;
            *(float4*)(R1 + (fi >> 10) * 1028 + (fi & 1023)) = feg[idx];
        }
    }
    __syncthreads();

    // ---- dense 16->64 + complex recombine ----
    // thread = (n8l = tid>>5, uq = (tid>>3)&3, bpp = tid&7): 2 b's, 16 u's
    {
        const int n8l = tid >> 5;
        const int uq  = (tid >> 3) & 3;
        const int bpp = tid & 7;
        float fv[4][16];
#pragma unroll
        for (int vv = 0; vv < 4; vv++) {
            const int v = n8l * 32 + 4 * bpp + vv;
#pragma unroll
            for (int cq = 0; cq < 4; cq++) {
                float4 x = *(const float4*)(R2 + paddr(v, cq));
                fv[vv][4 * cq] = x.x; fv[vv][4 * cq + 1] = x.y;
                fv[vv][4 * cq + 2] = x.z; fv[vv][4 * cq + 3] = x.w;
            }
        }
        const float* FEn = R1 + n8l * 1028 + uq * 16;
        float r0a[8], r1a[8], i1a[8], r0b[8], r1b[8], i1b[8];
#pragma unroll
        for (int j = 0; j < 8; j++) {
            r0a[j] = 0.f; r1a[j] = 0.f; i1a[j] = 0.f;
            r0b[j] = 0.f; r1b[j] = 0.f; i1b[j] = 0.f;
        }
#pragma unroll
        for (int c = 0; c < 16; c++) {
            const float* wr = FEn + c * 64;
            float4 wa = *(const float4*)(wr);
            float4 wb = *(const float4*)(wr + 4);
            float4 wc = *(const float4*)(wr + 8);
            float4 wd = *(const float4*)(wr + 12);
            const float we[8] = {wa.x, wa.z, wb.x, wb.z, wc.x, wc.z, wd.x, wd.z};
            const float wo[8] = {wa.y, wa.w, wb.y, wb.w, wc.y, wc.w, wd.y, wd.w};
            float fe0 = fv[0][c], fo0 = fv[1][c], fe1 = fv[2][c], fo1 = fv[3][c];
#pragma unroll
            for (int j = 0; j < 8; j++) {
                r0a[j] += fe0 * we[j];  r1a[j] += fe0 * wo[j];  i1a[j] += fo0 * wo[j];
                r0b[j] += fe1 * we[j];  r1b[j] += fe1 * wo[j];  i1b[j] += fo1 * wo[j];
            }
        }
        const int n8g = n4 * 16 + n8l;
        const int b0  = chunk * 16 + 2 * bpp;
#pragma unroll
        for (int pp = 0; pp < 2; pp++) {
            const float* r0 = pp ? r0b : r0a;
            const float* r1 = pp ? r1b : r1a;
            const float* i1 = pp ? i1b : i1a;
            float* o0p = out + (size_t)(b0 + pp) * 8192 + n8g * 32 + uq * 8;
            float* o1p = o0p + OUT_HALF;
            *(float4*)(o0p)     = make_float4((r0[0] - i1[0]) * (1.f / 16384.f), (r0[1] - i1[1]) * (1.f / 16384.f),
                                              (r0[2] - i1[2]) * (1.f / 16384.f), (r0[3] - i1[3]) * (1.f / 16384.f));
            *(float4*)(o0p + 4) = make_float4((r0[4] - i1[4]) * (1.f / 16384.f), (r0[5] - i1[5]) * (1.f / 16384.f),
                                              (r0[6] - i1[6]) * (1.f / 16384.f), (r0[7] - i1[7]) * (1.f / 16384.f));
            *(float4*)(o1p)     = make_float4(r1[0], r1[1], r1[2], r1[3]);
            *(float4*)(o1p + 4) = make_float4(r1[4], r1[5], r1[6], r1[7]);
        }
    }
}

extern "C" void kernel_launch(void* const* d_in, const int* in_sizes, int n_in,
                              void* d_out, int out_size, void* d_ws, size_t ws_size,
                              hipStream_t stream) {
    const float* in_data   = (const float*)d_in[0];
    const float* mid_dense = (const float*)d_in[1];
    const float* in_filter = (const float*)d_in[2];
    const float* in_bias   = (const float*)d_in[3];
    const float* filters   = (const float*)d_in[4];
    const float* biases    = (const float*)d_in[5];
    const float* fea_dense = (const float*)d_in[6];
    float* out = (float*)d_out;
    float* S3  = (float*)d_ws;   // 512 bi x 256 vec x 16 floats = 8 MB

    ibf_A<<<dim3(256, 2), 256, 0, stream>>>(in_data, mid_dense, in_filter, in_bias,
                                            filters, biases, S3);
    ibf_B<<<dim3(16, 16), 512, 0, stream>>>(filters, biases, fea_dense, S3, out);
}

// Round 4
// 64.884 us; speedup vs baseline: 1.5048x; 1.5048x over previous
//
#include <hip/hip_runtime.h>

// InvButterflyLayer: B=256, MID=16384, OUT=16384, C=16, NLVL=8.
// Live cone: level lvl only needs t < 2^(8-lvl); level 0 t<256 -> x[0:8224).
//
// Kernel A: block = b (256 blocks x 256 thr). Levels 0..3, BOTH complex halves
//   per thread (shares in_data loads, 2x weight reuse). Weights lvl1-3 staged
//   in LDS, read as wave-broadcast b128 (uniform or 2-way per wave -> free).
//   in_filter (level 0) via s_load: 32 FMA per weight float hides K$ latency.
//   State ping-pong in LDS. Writes S3[bi][vec][16] to d_ws.
// Kernel B: block = (n4, bi-chunk of 32) (256 blocks x 512 thr). Levels 4..8 +
//   16->64 dense + complex recombine. All weights (31 nodes) + FE staged in
//   LDS; zero in-loop s_loads.
//
// LDS state layout (verified R3, conflicts=0): vector v = 4 float4 chunks;
// chunk q at (v>>1)*32 + ((((v&1)<<2)|q) ^ ((v>>1 ^ v>>4... see paddr)))*4.
// Bijective, b128-aligned, worst case 2-way (free).

#define OUT_HALF 2097152

__device__ __forceinline__ int paddr(int v, int q) {
    const int h    = v >> 1;
    const int slot = ((v & 1) << 2) | q;
    const int swz  = (h ^ (h >> 3)) & 7;
    return (h << 5) + ((slot ^ swz) << 2);
}

__device__ __forceinline__ void fma16(float* acc, float p, const float* w) {
#pragma unroll
    for (int d = 0; d < 16; d++) acc[d] += p * w[d];
}

__device__ __forceinline__ void store_relu(float* base, int v, const float* acc) {
#pragma unroll
    for (int q = 0; q < 4; q++) {
        *(float4*)(base + paddr(v, q)) =
            make_float4(fmaxf(acc[4 * q + 0], 0.f), fmaxf(acc[4 * q + 1], 0.f),
                        fmaxf(acc[4 * q + 2], 0.f), fmaxf(acc[4 * q + 3], 0.f));
    }
}

__global__ __launch_bounds__(256, 1)
void ibf_A(const float* __restrict__ in_data,
           const float* __restrict__ mid_dense,
           const float* __restrict__ in_filter,
           const float* __restrict__ in_bias,
           const float* __restrict__ filters,
           const float* __restrict__ biases,
           float* __restrict__ S3) {
    __shared__ __align__(16) float buf0[8192];   // 512 vec (row0: 0..255, row1: 256..511)
    __shared__ __align__(16) float buf1[8192];
    __shared__ __align__(16) float WL[7224];     // 14 nodes (lvl1:2, lvl2:4, lvl3:8) stride 516
    __shared__ float LB[224];

    const int tid = threadIdx.x;
    const int b   = blockIdx.x;

    // ---- stage lvl1-3 weights + biases (consumed after first barrier) ----
    for (int idx = tid; idx < 14 * 128; idx += 256) {
        const int nidx = idx >> 7, r = idx & 127;
        const int lvl  = (nidx < 2) ? 1 : ((nidx < 6) ? 2 : 3);
        const int n    = nidx - ((1 << lvl) - 2);
        float4 v = ((const float4*)(filters + (size_t)(lvl - 1) * 131072 + (size_t)n * 512))[r];
        ((float4*)(WL + nidx * 516))[r] = v;
    }
    if (tid < 224) {
        const int nidx = tid >> 4;
        const int lvl  = (nidx < 2) ? 1 : ((nidx < 6) ? 2 : 3);
        const int n    = nidx - ((1 << lvl) - 2);
        LB[tid] = biases[(size_t)(lvl - 1) * 4096 + n * 16 + (tid & 15)];
    }

    // ---- level 0: t = tid, 64-tap window, both complex halves ----
    {
        float acc0[16], acc1[16];
#pragma unroll
        for (int c = 0; c < 16; c++) { float bv = in_bias[c]; acc0[c] = bv; acc1[c] = bv; }
        const float4* inb = (const float4*)(in_data + ((size_t)b * 16384 + (size_t)32 * tid) * 2);
        const float4* mdb = (const float4*)(mid_dense + (size_t)(32 * tid) * 2);
#pragma unroll 8
        for (int w2 = 0; w2 < 32; w2++) {
            float4 iv = inb[w2];
            float4 mv = mdb[w2];
            const float* F0 = in_filter + w2 * 32;   // uniform -> s_load, 64 FMA/dwordx16
            fma16(acc0, iv.x * mv.x, F0);
            fma16(acc1, iv.y * mv.y, F0);
            fma16(acc0, iv.z * mv.z, F0 + 16);
            fma16(acc1, iv.w * mv.w, F0 + 16);
        }
        store_relu(buf0, tid, acc0);
        store_relu(buf0, 256 + tid, acc1);
    }
    __syncthreads();

    // ---- levels 1..3: LDS weights (broadcast b128), both rows per thread ----
    float* P = buf0;
    float* N = buf1;
#pragma unroll
    for (int lvl = 1; lvl <= 3; lvl++) {
        const int sh   = 8 - lvl;
        const int T    = 1 << sh;
        const int n    = tid >> sh;
        const int t    = tid & (T - 1);
        const int nidx = (1 << lvl) - 2 + n;
        const float* Wn = WL + nidx * 516;
        const float* bn = LB + nidx * 16;
        float acc0[16], acc1[16];
#pragma unroll
        for (int qb = 0; qb < 4; qb++) {
            float4 bv = *(const float4*)(bn + 4 * qb);
            acc0[4*qb] = bv.x; acc0[4*qb+1] = bv.y; acc0[4*qb+2] = bv.z; acc0[4*qb+3] = bv.w;
            acc1[4*qb] = bv.x; acc1[4*qb+1] = bv.y; acc1[4*qb+2] = bv.z; acc1[4*qb+3] = bv.w;
        }
        const int pb = (n >> 1) * (2 * T);
#pragma unroll
        for (int k = 0; k < 2; k++) {
            const int pv = pb + 2 * t + k;
#pragma unroll
            for (int cq = 0; cq < 4; cq++) {
                float4 p0 = *(const float4*)(P + paddr(pv, cq));
                float4 p1 = *(const float4*)(P + paddr(pv + 256, cq));
                const float* w0 = Wn + k * 256 + cq * 64;
                fma16(acc0, p0.x, w0);      fma16(acc1, p1.x, w0);
                fma16(acc0, p0.y, w0 + 16); fma16(acc1, p1.y, w0 + 16);
                fma16(acc0, p0.z, w0 + 32); fma16(acc1, p1.z, w0 + 32);
                fma16(acc0, p0.w, w0 + 48); fma16(acc1, p1.w, w0 + 48);
            }
        }
        if (lvl < 3) {
            store_relu(N, tid, acc0);
            store_relu(N, 256 + tid, acc1);
            __syncthreads();
            float* tmp = P; P = N; N = tmp;
        } else {
            // write S3 rows 2b (i=0) and 2b+1 (i=1), vec = tid
            float* d0 = S3 + ((size_t)(2 * b) * 256 + tid) * 16;
            float* d1 = S3 + ((size_t)(2 * b + 1) * 256 + tid) * 16;
#pragma unroll
            for (int qd = 0; qd < 4; qd++) {
                ((float4*)d0)[qd] = make_float4(fmaxf(acc0[4*qd], 0.f), fmaxf(acc0[4*qd+1], 0.f),
                                                fmaxf(acc0[4*qd+2], 0.f), fmaxf(acc0[4*qd+3], 0.f));
                ((float4*)d1)[qd] = make_float4(fmaxf(acc1[4*qd], 0.f), fmaxf(acc1[4*qd+1], 0.f),
                                                fmaxf(acc1[4*qd+2], 0.f), fmaxf(acc1[4*qd+3], 0.f));
            }
        }
    }
}

__global__ __launch_bounds__(512, 1)
void ibf_B(const float* __restrict__ filters,
           const float* __restrict__ biases,
           const float* __restrict__ fea_dense,
           const float* __restrict__ S3,
           float* __restrict__ out) {
    __shared__ __align__(16) float buf0[8192];   // 512 vec
    __shared__ __align__(16) float buf1[8192];
    __shared__ __align__(16) float WF[16448];    // 31 nodes stride 516; later FE 16x1028
    __shared__ float LB[496];

    const int tid   = threadIdx.x;
    const int n4    = blockIdx.x;   // 0..15
    const int chunk = blockIdx.y;   // 0..15
    const int bi0   = chunk * 32;
    const int n3    = n4 >> 1;

    // ---- stage lvl3 state chunk (vec = t3*32 + bi_l) ----
    for (int idx = tid; idx < 4096; idx += 512) {
        const int bi_l = idx >> 7;
        const int r    = idx & 127;
        const int t3   = r >> 2;
        const int q    = r & 3;
        float4 v = *(const float4*)(S3 + ((size_t)(bi0 + bi_l) * 256 + n3 * 32 + t3) * 16 + 4 * q);
        *(float4*)(buf0 + paddr(t3 * 32 + bi_l, q)) = v;
    }
    // ---- stage lvl4-8 weights (31 nodes) + biases ----
    for (int idx = tid; idx < 31 * 128; idx += 512) {
        const int nidx = idx >> 7, r = idx & 127;
        const int lm4  = 31 - __clz(nidx + 1);          // level - 4
        const int n    = nidx + 1 - (1 << lm4);
        const int gn   = (lm4 + 3) * 256 + (n4 << lm4) + n;
        float4 v = ((const float4*)(filters + (size_t)gn * 512))[r];
        ((float4*)(WF + nidx * 516))[r] = v;
    }
    if (tid < 496) {
        const int nidx = tid >> 4;
        const int lm4  = 31 - __clz(nidx + 1);
        const int n    = nidx + 1 - (1 << lm4);
        const int gn   = (lm4 + 3) * 256 + (n4 << lm4) + n;
        LB[tid] = biases[(size_t)gn * 16 + (tid & 15)];
    }
    __syncthreads();

    // ---- levels 4..8: LDS weights (broadcast), ping-pong state ----
    float* P = buf0;
    float* N = buf1;
#pragma unroll
    for (int lvl = 4; lvl <= 8; lvl++) {
        const int Tsh   = 8 - lvl;                  // 4,3,2,1,0
        const int n_loc = tid >> (Tsh + 5);
        const int t     = (tid >> 5) & ((1 << Tsh) - 1);
        const int bi    = tid & 31;
        const int nidx  = (1 << (lvl - 4)) - 1 + n_loc;
        const float* Wn = WF + nidx * 516;
        const float* bn = LB + nidx * 16;
        float acc[16];
#pragma unroll
        for (int qb = 0; qb < 4; qb++) {
            float4 bv = *(const float4*)(bn + 4 * qb);
            acc[4*qb] = bv.x; acc[4*qb+1] = bv.y; acc[4*qb+2] = bv.z; acc[4*qb+3] = bv.w;
        }
        const int pb = (n_loc >> 1) << (Tsh + 6);   // parent node * (2T*32)
#pragma unroll
        for (int k = 0; k < 2; k++) {
            const int pv = pb + (2 * t + k) * 32 + bi;
#pragma unroll
            for (int cq = 0; cq < 4; cq++) {
                float4 pc = *(const float4*)(P + paddr(pv, cq));
                const float* w0 = Wn + k * 256 + cq * 64;
                fma16(acc, pc.x, w0);
                fma16(acc, pc.y, w0 + 16);
                fma16(acc, pc.z, w0 + 32);
                fma16(acc, pc.w, w0 + 48);
            }
        }
        store_relu(N, tid, acc);
        __syncthreads();
        float* tmp = P; P = N; N = tmp;
    }
    // feat now in P (= buf1 after 5 swaps)

    // ---- stage fea_dense (16 nodes x 1024) into WF, node stride 1028 ----
    {
        const float4* feg = (const float4*)(fea_dense + (size_t)n4 * 16384);
        for (int idx = tid; idx < 4096; idx += 512) {
            const int fi = idx * 4;
            *(float4*)(WF + (fi >> 10) * 1028 + (fi & 1023)) = feg[idx];
        }
    }
    __syncthreads();

    // ---- dense 16->64 + complex recombine ----
    // thread = (n8l = tid>>5, uq = (tid>>3)&3, bpp = tid&7): 2 b's, 8 u-pairs
    {
        const int n8l = tid >> 5;
        const int uq  = (tid >> 3) & 3;
        const int bpp = tid & 7;
        float fv[4][16];
#pragma unroll
        for (int vv = 0; vv < 4; vv++) {
            const int v = n8l * 32 + 4 * bpp + vv;
#pragma unroll
            for (int cq = 0; cq < 4; cq++) {
                float4 x = *(const float4*)(P + paddr(v, cq));
                fv[vv][4 * cq] = x.x; fv[vv][4 * cq + 1] = x.y;
                fv[vv][4 * cq + 2] = x.z; fv[vv][4 * cq + 3] = x.w;
            }
        }
        const float* FEn = WF + n8l * 1028 + uq * 16;
        float r0a[8], r1a[8], i1a[8], r0b[8], r1b[8], i1b[8];
#pragma unroll
        for (int j = 0; j < 8; j++) {
            r0a[j] = 0.f; r1a[j] = 0.f; i1a[j] = 0.f;
            r0b[j] = 0.f; r1b[j] = 0.f; i1b[j] = 0.f;
        }
#pragma unroll
        for (int c = 0; c < 16; c++) {
            const float* wr = FEn + c * 64;
            float4 wa = *(const float4*)(wr);
            float4 wb = *(const float4*)(wr + 4);
            float4 wc = *(const float4*)(wr + 8);
            float4 wd = *(const float4*)(wr + 12);
            const float we[8] = {wa.x, wa.z, wb.x, wb.z, wc.x, wc.z, wd.x, wd.z};
            const float wo[8] = {wa.y, wa.w, wb.y, wb.w, wc.y, wc.w, wd.y, wd.w};
            float fe0 = fv[0][c], fo0 = fv[1][c], fe1 = fv[2][c], fo1 = fv[3][c];
#pragma unroll
            for (int j = 0; j < 8; j++) {
                r0a[j] += fe0 * we[j];  r1a[j] += fe0 * wo[j];  i1a[j] += fo0 * wo[j];
                r0b[j] += fe1 * we[j];  r1b[j] += fe1 * wo[j];  i1b[j] += fo1 * wo[j];
            }
        }
        const int n8g = n4 * 16 + n8l;
        const int b0  = chunk * 16 + 2 * bpp;
#pragma unroll
        for (int pp = 0; pp < 2; pp++) {
            const float* r0 = pp ? r0b : r0a;
            const float* r1 = pp ? r1b : r1a;
            const float* i1 = pp ? i1b : i1a;
            float* o0p = out + (size_t)(b0 + pp) * 8192 + n8g * 32 + uq * 8;
            float* o1p = o0p + OUT_HALF;
            *(float4*)(o0p)     = make_float4((r0[0] - i1[0]) * (1.f / 16384.f), (r0[1] - i1[1]) * (1.f / 16384.f),
                                              (r0[2] - i1[2]) * (1.f / 16384.f), (r0[3] - i1[3]) * (1.f / 16384.f));
            *(float4*)(o0p + 4) = make_float4((r0[4] - i1[4]) * (1.f / 16384.f), (r0[5] - i1[5]) * (1.f / 16384.f),
                                              (r0[6] - i1[6]) * (1.f / 16384.f), (r0[7] - i1[7]) * (1.f / 16384.f));
            *(float4*)(o1p)     = make_float4(r1[0], r1[1], r1[2], r1[3]);
            *(float4*)(o1p + 4) = make_float4(r1[4], r1[5], r1[6], r1[7]);
        }
    }
}

extern "C" void kernel_launch(void* const* d_in, const int* in_sizes, int n_in,
                              void* d_out, int out_size, void* d_ws, size_t ws_size,
                              hipStream_t stream) {
    const float* in_data   = (const float*)d_in[0];
    const float* mid_dense = (const float*)d_in[1];
    const float* in_filter = (const float*)d_in[2];
    const float* in_bias   = (const float*)d_in[3];
    const float* filters   = (const float*)d_in[4];
    const float* biases    = (const float*)d_in[5];
    const float* fea_dense = (const float*)d_in[6];
    float* out = (float*)d_out;
    float* S3  = (float*)d_ws;   // 512 bi x 256 vec x 16 floats = 8 MB

    ibf_A<<<256, 256, 0, stream>>>(in_data, mid_dense, in_filter, in_bias,
                                   filters, biases, S3);
    ibf_B<<<dim3(16, 16), 512, 0, stream>>>(filters, biases, fea_dense, S3, out);
}